// Round 2
// baseline (1138.710 us; speedup 1.0000x reference)
//
#include <hip/hip_runtime.h>
#include <math.h>

#define N_NODES 50000
#define M_EDGES 800000
#define INP 256
#define KCAP 8
#define FAC 12
#define KF 96            // K*FAC
#define ROUTIT 6

// ---------------- ws layout (bytes) ----------------
#define OFF_ZA      0u
#define OFF_ZB      19200000u
#define OFF_ROWPTR  38400000u   // 50001 ints (padded)
#define OFF_PARTIAL 38600016u   // 50000 ints
#define OFF_CURSOR  38800016u   // 50000 ints (also used as counts)
#define OFF_BSUMS   39000016u   // 256 ints
#define OFF_CSR     39001040u   // 800000 ints
#define OFF_WT      42201040u   // 256*96 floats

// ---------- W transpose: Wt[i][k*12+f] = W[k][i][f] ----------
__global__ void wt_transpose(const float* __restrict__ W, float* __restrict__ Wt) {
    int idx = blockIdx.x * 256 + threadIdx.x;
    if (idx >= INP * KF) return;
    int i = idx / KF, kf = idx % KF;
    int k = kf / FAC, f = kf % FAC;
    Wt[i * KF + kf] = W[(k * INP + i) * FAC + f];
}

// ---------- init: Z0[n][kf] = relu(X[n,:] . Wt[:,kf] + b[kf]) ----------
// block 192 = 2 groups x 96 threads; each thread computes 4 nodes (W reuse)
__global__ __launch_bounds__(192) void init_proj(const float* __restrict__ X,
                                                 const float* __restrict__ Wt,
                                                 const float* __restrict__ b,
                                                 float* __restrict__ Z0) {
    int kf  = threadIdx.x % KF;
    int grp = threadIdx.x / KF;
    int n0  = blockIdx.x * 8 + grp * 4;
    const float* x0 = X + (size_t)n0 * INP;
    float acc0 = 0.f, acc1 = 0.f, acc2 = 0.f, acc3 = 0.f;
    #pragma unroll 8
    for (int i = 0; i < INP; ++i) {
        float w = Wt[i * KF + kf];
        acc0 = fmaf(x0[i],           w, acc0);
        acc1 = fmaf(x0[INP + i],     w, acc1);
        acc2 = fmaf(x0[2 * INP + i], w, acc2);
        acc3 = fmaf(x0[3 * INP + i], w, acc3);
    }
    float bb = b[kf];
    Z0[(size_t)(n0 + 0) * KF + kf] = fmaxf(acc0 + bb, 0.f);
    Z0[(size_t)(n0 + 1) * KF + kf] = fmaxf(acc1 + bb, 0.f);
    Z0[(size_t)(n0 + 2) * KF + kf] = fmaxf(acc2 + bb, 0.f);
    Z0[(size_t)(n0 + 3) * KF + kf] = fmaxf(acc3 + bb, 0.f);
}

// ---------- prep: per-capsule l2norm ----------
__global__ void prep_norm(const float* __restrict__ Z0, float* __restrict__ zb) {
    int cap = blockIdx.x * blockDim.x + threadIdx.x;
    if (cap >= N_NODES * KCAP) return;
    const float4* p = (const float4*)(Z0 + (size_t)cap * FAC);
    float4 a = p[0], bq = p[1], cq = p[2];
    float ss = a.x*a.x + a.y*a.y + a.z*a.z + a.w*a.w
             + bq.x*bq.x + bq.y*bq.y + bq.z*bq.z + bq.w*bq.w
             + cq.x*cq.x + cq.y*cq.y + cq.z*cq.z + cq.w*cq.w;
    float inv = 1.0f / sqrtf(ss + 1e-12f);
    float4* o = (float4*)(zb + (size_t)cap * FAC);
    float4 r0, r1, r2;
    r0.x=a.x*inv;  r0.y=a.y*inv;  r0.z=a.z*inv;  r0.w=a.w*inv;
    r1.x=bq.x*inv; r1.y=bq.y*inv; r1.z=bq.z*inv; r1.w=bq.w*inv;
    r2.x=cq.x*inv; r2.y=cq.y*inv; r2.z=cq.z*inv; r2.w=cq.w*inv;
    o[0]=r0; o[1]=r1; o[2]=r2;
}

// ---------- CSR build ----------
__global__ void zero_counts(int* __restrict__ counts) {
    int i = blockIdx.x * 256 + threadIdx.x;
    if (i < N_NODES) counts[i] = 0;
}
__global__ void hist(const int* __restrict__ dst, int* __restrict__ counts) {
    int e = blockIdx.x * 256 + threadIdx.x;
    if (e < M_EDGES) atomicAdd(&counts[dst[e]], 1);
}
__global__ void scan1(const int* __restrict__ counts, int* __restrict__ partial,
                      int* __restrict__ bsums) {
    __shared__ int s[256];
    int t = threadIdx.x;
    int i = blockIdx.x * 256 + t;
    int v = (i < N_NODES) ? counts[i] : 0;
    s[t] = v; __syncthreads();
    for (int off = 1; off < 256; off <<= 1) {
        int tmp = (t >= off) ? s[t - off] : 0;
        __syncthreads();
        s[t] += tmp;
        __syncthreads();
    }
    if (i < N_NODES) partial[i] = s[t];
    if (t == 255) bsums[blockIdx.x] = s[t];
}
__global__ void scan2(int* __restrict__ bs, int nb) {
    __shared__ int s[256];
    int t = threadIdx.x;
    int v = (t < nb) ? bs[t] : 0;
    s[t] = v; __syncthreads();
    for (int off = 1; off < 256; off <<= 1) {
        int tmp = (t >= off) ? s[t - off] : 0;
        __syncthreads();
        s[t] += tmp;
        __syncthreads();
    }
    if (t < nb) bs[t] = s[t] - v;  // exclusive
}
__global__ void finalize_rp(const int* __restrict__ partial, const int* __restrict__ boffs,
                            int* __restrict__ row_ptr) {
    int i = blockIdx.x * 256 + threadIdx.x;
    if (i < N_NODES) row_ptr[i + 1] = partial[i] + boffs[i >> 8];
    if (i == 0) row_ptr[0] = 0;
}
__global__ void cursor_init(const int* __restrict__ row_ptr, int* __restrict__ cursor) {
    int i = blockIdx.x * 256 + threadIdx.x;
    if (i < N_NODES) cursor[i] = row_ptr[i];
}
__global__ void csr_fill(const int* __restrict__ src, const int* __restrict__ dst,
                         int* __restrict__ cursor, int* __restrict__ csr) {
    int e = blockIdx.x * 256 + threadIdx.x;
    if (e < M_EDGES) {
        int d = dst[e];
        int pos = atomicAdd(&cursor[d], 1);
        csr[pos] = src[e];
    }
}

// ---------- routing layer: one wave per node ----------
// lane = g*8 + k : g = edge slot (0..7), k = capsule (0..7)
// z,c,agg all 12 floats in-lane (own capsule). 6 routing iterations in-register.
__global__ __launch_bounds__(256) void route(const float* __restrict__ zin,
                                             float* __restrict__ znext,
                                             float* __restrict__ dout,
                                             const int* __restrict__ row_ptr,
                                             const int* __restrict__ csr,
                                             int write_out) {
    int node = (int)((blockIdx.x * blockDim.x + threadIdx.x) >> 6);
    if (node >= N_NODES) return;
    int lane = threadIdx.x & 63;
    int g = lane >> 3;
    int k = lane & 7;

    const float* zr = zin + (size_t)node * KF + k * FAC;
    float z[12], c[12];
    #pragma unroll
    for (int q = 0; q < 3; ++q) {
        float4 t = ((const float4*)zr)[q];
        z[q*4+0]=t.x; z[q*4+1]=t.y; z[q*4+2]=t.z; z[q*4+3]=t.w;
    }
    #pragma unroll
    for (int d = 0; d < 12; ++d) c[d] = z[d];

    int base = row_ptr[node], end = row_ptr[node + 1];

    for (int it = 0; it < ROUTIT; ++it) {
        float agg[12];
        #pragma unroll
        for (int d = 0; d < 12; ++d) agg[d] = 0.f;

        for (int t0 = base; t0 < end; t0 += 8) {
            int e = t0 + g;
            bool act = e < end;
            int s = 0;
            if (act) s = csr[e];
            const float4* zs4 = (const float4*)(zin + (size_t)s * KF + k * FAC);
            float zs[12];
            #pragma unroll
            for (int q = 0; q < 3; ++q) {
                float4 t = zs4[q];
                zs[q*4+0]=t.x; zs[q*4+1]=t.y; zs[q*4+2]=t.z; zs[q*4+3]=t.w;
            }
            float att = 0.f;
            #pragma unroll
            for (int d = 0; d < 12; ++d) att = fmaf(zs[d], c[d], att);
            // softmax over the 8 capsules (lanes k within subgroup)
            float mx = att;
            mx = fmaxf(mx, __shfl_xor(mx, 1));
            mx = fmaxf(mx, __shfl_xor(mx, 2));
            mx = fmaxf(mx, __shfl_xor(mx, 4));
            float ex = __expf(att - mx);
            float sm = ex;
            sm += __shfl_xor(sm, 1);
            sm += __shfl_xor(sm, 2);
            sm += __shfl_xor(sm, 4);
            float p = ex / sm;
            if (act) {
                #pragma unroll
                for (int d = 0; d < 12; ++d) agg[d] = fmaf(p, zs[d], agg[d]);
            }
        }
        // reduce agg across the 8 edge-slot subgroups
        #pragma unroll
        for (int mask = 8; mask <= 32; mask <<= 1) {
            #pragma unroll
            for (int d = 0; d < 12; ++d) agg[d] += __shfl_xor(agg[d], mask);
        }
        // c = l2norm(z + agg) per capsule (in-lane)
        float v[12], ss = 0.f;
        #pragma unroll
        for (int d = 0; d < 12; ++d) { v[d] = z[d] + agg[d]; ss = fmaf(v[d], v[d], ss); }
        float inv = 1.0f / sqrtf(ss + 1e-12f);
        #pragma unroll
        for (int d = 0; d < 12; ++d) c[d] = v[d] * inv;
    }

    if (g == 0) {
        // relu then l2norm(relu) for next layer's z
        float r[12], ss = 0.f;
        #pragma unroll
        for (int d = 0; d < 12; ++d) { r[d] = fmaxf(c[d], 0.f); ss = fmaf(r[d], r[d], ss); }
        float inv = 1.0f / sqrtf(ss + 1e-12f);
        float* zo = znext + (size_t)node * KF + k * FAC;
        #pragma unroll
        for (int q = 0; q < 3; ++q) {
            float4 t;
            t.x = r[q*4+0]*inv; t.y = r[q*4+1]*inv; t.z = r[q*4+2]*inv; t.w = r[q*4+3]*inv;
            ((float4*)zo)[q] = t;
        }
        if (write_out) {
            float* oo = dout + (size_t)node * KF + k * FAC;
            #pragma unroll
            for (int q = 0; q < 3; ++q) {
                float4 t;
                t.x = r[q*4+0]; t.y = r[q*4+1]; t.z = r[q*4+2]; t.w = r[q*4+3];
                ((float4*)oo)[q] = t;
            }
        }
    }
}

extern "C" void kernel_launch(void* const* d_in, const int* in_sizes, int n_in,
                              void* d_out, int out_size, void* d_ws, size_t ws_size,
                              hipStream_t stream) {
    const float* X     = (const float*)d_in[0];
    const int*   edges = (const int*)d_in[1];
    const float* W     = (const float*)d_in[2];
    const float* b     = (const float*)d_in[3];
    float* out = (float*)d_out;
    char* ws = (char*)d_ws;

    float* zA      = (float*)(ws + OFF_ZA);
    float* zB      = (float*)(ws + OFF_ZB);
    int*   row_ptr = (int*)(ws + OFF_ROWPTR);
    int*   partial = (int*)(ws + OFF_PARTIAL);
    int*   cursor  = (int*)(ws + OFF_CURSOR);
    int*   bsums   = (int*)(ws + OFF_BSUMS);
    int*   csr     = (int*)(ws + OFF_CSR);
    float* Wt      = (float*)(ws + OFF_WT);

    const int* src = edges;            // edges[0, :]
    const int* dst = edges + M_EDGES;  // edges[1, :]

    // init projection + per-capsule normalize  (Z0 raw -> zB, normalized -> zA)
    wt_transpose<<<96, 256, 0, stream>>>(W, Wt);
    init_proj<<<6250, 192, 0, stream>>>(X, Wt, b, zB);
    prep_norm<<<(N_NODES * KCAP + 255) / 256, 256, 0, stream>>>(zB, zA);

    // CSR by dst
    zero_counts<<<196, 256, 0, stream>>>(cursor);
    hist<<<(M_EDGES + 255) / 256, 256, 0, stream>>>(dst, cursor);
    scan1<<<196, 256, 0, stream>>>(cursor, partial, bsums);
    scan2<<<1, 256, 0, stream>>>(bsums, 196);
    finalize_rp<<<196, 256, 0, stream>>>(partial, bsums, row_ptr);
    cursor_init<<<196, 256, 0, stream>>>(row_ptr, cursor);
    csr_fill<<<(M_EDGES + 255) / 256, 256, 0, stream>>>(src, dst, cursor, csr);

    // 4 routing layers, ping-pong z buffers; last layer also writes d_out
    route<<<12500, 256, 0, stream>>>(zA, zB, nullptr, row_ptr, csr, 0);
    route<<<12500, 256, 0, stream>>>(zB, zA, nullptr, row_ptr, csr, 0);
    route<<<12500, 256, 0, stream>>>(zA, zB, nullptr, row_ptr, csr, 0);
    route<<<12500, 256, 0, stream>>>(zB, zA, out, row_ptr, csr, 1);
}

// Round 3
// 966.683 us; speedup vs baseline: 1.1780x; 1.1780x over previous
//
#include <hip/hip_runtime.h>
#include <math.h>

#define N_NODES 50000
#define M_EDGES 800000
#define INP 256
#define KCAP 8
#define FAC 12
#define KF 96            // K*FAC
#define ROUTIT 6
#define DMAX 32          // register-cached edges per node (4 slots x 8 subgroups)

// ---------------- ws layout (bytes) ----------------
#define OFF_ZA      0u
#define OFF_ZB      19200000u
#define OFF_ROWPTR  38400000u   // 50001 ints (padded)
#define OFF_PARTIAL 38600016u   // 50000 ints
#define OFF_CURSOR  38800016u   // 50000 ints (also used as counts)
#define OFF_BSUMS   39000016u   // 256 ints
#define OFF_CSR     39001040u   // 800000 ints
#define OFF_WT      42201040u   // 256*96 floats

// ---------- W transpose: Wt[i][kf] = W[k][i][f]  (i-major, kf-minor) ----------
__global__ void wt_transpose(const float* __restrict__ W, float* __restrict__ Wt) {
    int idx = blockIdx.x * 256 + threadIdx.x;
    if (idx >= INP * KF) return;
    int i = idx / KF, kf = idx % KF;
    int k = kf / FAC, f = kf % FAC;
    Wt[i * KF + kf] = W[(k * INP + i) * FAC + f];
}

// ---------- init: Z0[n][kf] = relu(X[n,:].Wt[:,kf] + b[kf]) ----------
// register-blocked 4 nodes x 4 kf per thread; block 192 = 8 node-quads x 24 kf-quads
__global__ __launch_bounds__(192) void init_proj(const float* __restrict__ X,
                                                 const float* __restrict__ Wt,
                                                 const float* __restrict__ b,
                                                 float* __restrict__ Z0) {
    int nq  = threadIdx.x / 24;          // 0..7
    int kfq = threadIdx.x % 24;          // 0..23
    int nb  = blockIdx.x * 32 + nq * 4;  // node base (4 nodes)
    int kf0 = kfq * 4;

    int nn[4];
    #pragma unroll
    for (int m = 0; m < 4; ++m) {
        int n = nb + m;
        nn[m] = n < N_NODES ? n : N_NODES - 1;  // clamp; discard at write
    }

    float acc[4][4];
    #pragma unroll
    for (int m = 0; m < 4; ++m)
        #pragma unroll
        for (int cc = 0; cc < 4; ++cc) acc[m][cc] = 0.f;

    for (int i4 = 0; i4 < INP / 4; ++i4) {
        float4 xv[4];
        #pragma unroll
        for (int m = 0; m < 4; ++m)
            xv[m] = ((const float4*)(X + (size_t)nn[m] * INP))[i4];
        float4 wv[4];
        #pragma unroll
        for (int r = 0; r < 4; ++r)
            wv[r] = *(const float4*)(Wt + (size_t)(i4 * 4 + r) * KF + kf0);
        #pragma unroll
        for (int m = 0; m < 4; ++m) {
            acc[m][0] = fmaf(xv[m].x, wv[0].x, acc[m][0]);
            acc[m][1] = fmaf(xv[m].x, wv[0].y, acc[m][1]);
            acc[m][2] = fmaf(xv[m].x, wv[0].z, acc[m][2]);
            acc[m][3] = fmaf(xv[m].x, wv[0].w, acc[m][3]);
            acc[m][0] = fmaf(xv[m].y, wv[1].x, acc[m][0]);
            acc[m][1] = fmaf(xv[m].y, wv[1].y, acc[m][1]);
            acc[m][2] = fmaf(xv[m].y, wv[1].z, acc[m][2]);
            acc[m][3] = fmaf(xv[m].y, wv[1].w, acc[m][3]);
            acc[m][0] = fmaf(xv[m].z, wv[2].x, acc[m][0]);
            acc[m][1] = fmaf(xv[m].z, wv[2].y, acc[m][1]);
            acc[m][2] = fmaf(xv[m].z, wv[2].z, acc[m][2]);
            acc[m][3] = fmaf(xv[m].z, wv[2].w, acc[m][3]);
            acc[m][0] = fmaf(xv[m].w, wv[3].x, acc[m][0]);
            acc[m][1] = fmaf(xv[m].w, wv[3].y, acc[m][1]);
            acc[m][2] = fmaf(xv[m].w, wv[3].z, acc[m][2]);
            acc[m][3] = fmaf(xv[m].w, wv[3].w, acc[m][3]);
        }
    }

    float4 bv = *(const float4*)(b + kf0);
    #pragma unroll
    for (int m = 0; m < 4; ++m) {
        int n = nb + m;
        if (n < N_NODES) {
            float4 o;
            o.x = fmaxf(acc[m][0] + bv.x, 0.f);
            o.y = fmaxf(acc[m][1] + bv.y, 0.f);
            o.z = fmaxf(acc[m][2] + bv.z, 0.f);
            o.w = fmaxf(acc[m][3] + bv.w, 0.f);
            *(float4*)(Z0 + (size_t)n * KF + kf0) = o;
        }
    }
}

// ---------- prep: per-capsule l2norm ----------
__global__ void prep_norm(const float* __restrict__ Z0, float* __restrict__ zb) {
    int cap = blockIdx.x * blockDim.x + threadIdx.x;
    if (cap >= N_NODES * KCAP) return;
    const float4* p = (const float4*)(Z0 + (size_t)cap * FAC);
    float4 a = p[0], bq = p[1], cq = p[2];
    float ss = a.x*a.x + a.y*a.y + a.z*a.z + a.w*a.w
             + bq.x*bq.x + bq.y*bq.y + bq.z*bq.z + bq.w*bq.w
             + cq.x*cq.x + cq.y*cq.y + cq.z*cq.z + cq.w*cq.w;
    float inv = rsqrtf(ss + 1e-12f);
    float4* o = (float4*)(zb + (size_t)cap * FAC);
    float4 r0, r1, r2;
    r0.x=a.x*inv;  r0.y=a.y*inv;  r0.z=a.z*inv;  r0.w=a.w*inv;
    r1.x=bq.x*inv; r1.y=bq.y*inv; r1.z=bq.z*inv; r1.w=bq.w*inv;
    r2.x=cq.x*inv; r2.y=cq.y*inv; r2.z=cq.z*inv; r2.w=cq.w*inv;
    o[0]=r0; o[1]=r1; o[2]=r2;
}

// ---------- CSR build ----------
__global__ void zero_counts(int* __restrict__ counts) {
    int i = blockIdx.x * 256 + threadIdx.x;
    if (i < N_NODES) counts[i] = 0;
}
__global__ void hist(const int* __restrict__ dst, int* __restrict__ counts) {
    int e = blockIdx.x * 256 + threadIdx.x;
    if (e < M_EDGES) atomicAdd(&counts[dst[e]], 1);
}
__global__ void scan1(const int* __restrict__ counts, int* __restrict__ partial,
                      int* __restrict__ bsums) {
    __shared__ int s[256];
    int t = threadIdx.x;
    int i = blockIdx.x * 256 + t;
    int v = (i < N_NODES) ? counts[i] : 0;
    s[t] = v; __syncthreads();
    for (int off = 1; off < 256; off <<= 1) {
        int tmp = (t >= off) ? s[t - off] : 0;
        __syncthreads();
        s[t] += tmp;
        __syncthreads();
    }
    if (i < N_NODES) partial[i] = s[t];
    if (t == 255) bsums[blockIdx.x] = s[t];
}
__global__ void scan2(int* __restrict__ bs, int nb) {
    __shared__ int s[256];
    int t = threadIdx.x;
    int v = (t < nb) ? bs[t] : 0;
    s[t] = v; __syncthreads();
    for (int off = 1; off < 256; off <<= 1) {
        int tmp = (t >= off) ? s[t - off] : 0;
        __syncthreads();
        s[t] += tmp;
        __syncthreads();
    }
    if (t < nb) bs[t] = s[t] - v;  // exclusive
}
__global__ void finalize_rp(const int* __restrict__ partial, const int* __restrict__ boffs,
                            int* __restrict__ row_ptr) {
    int i = blockIdx.x * 256 + threadIdx.x;
    if (i < N_NODES) row_ptr[i + 1] = partial[i] + boffs[i >> 8];
    if (i == 0) row_ptr[0] = 0;
}
__global__ void cursor_init(const int* __restrict__ row_ptr, int* __restrict__ cursor) {
    int i = blockIdx.x * 256 + threadIdx.x;
    if (i < N_NODES) cursor[i] = row_ptr[i];
}
__global__ void csr_fill(const int* __restrict__ src, const int* __restrict__ dst,
                         int* __restrict__ cursor, int* __restrict__ csr) {
    int e = blockIdx.x * 256 + threadIdx.x;
    if (e < M_EDGES) {
        int d = dst[e];
        int pos = atomicAdd(&cursor[d], 1);
        csr[pos] = src[e];
    }
}

// ---------- routing layer: one wave per node, neighborhood cached in VGPRs ----------
// lane = g*8 + k : g = edge slot (0..7), k = capsule (0..7)
// Gather z[src] for up to DMAX=32 edges ONCE into zc[4][12]; all 6 routing
// iterations are then pure register math (no loads). deg>32 tail -> global path.
__global__ __launch_bounds__(256, 4) void route(const float* __restrict__ zin,
                                                float* __restrict__ znext,
                                                float* __restrict__ dout,
                                                const int* __restrict__ row_ptr,
                                                const int* __restrict__ csr,
                                                int write_out) {
    int node = (int)((blockIdx.x * blockDim.x + threadIdx.x) >> 6);
    if (node >= N_NODES) return;
    int lane = threadIdx.x & 63;
    int g = lane >> 3;
    int k = lane & 7;

    const float4* zr = (const float4*)(zin + (size_t)node * KF + k * FAC);
    float z[12], c[12];
    #pragma unroll
    for (int q = 0; q < 3; ++q) {
        float4 t = zr[q];
        z[q*4+0]=t.x; z[q*4+1]=t.y; z[q*4+2]=t.z; z[q*4+3]=t.w;
    }
    #pragma unroll
    for (int d = 0; d < 12; ++d) c[d] = z[d];

    int base = row_ptr[node], end = row_ptr[node + 1];
    int deg = end - base;
    int degc = deg < DMAX ? deg : DMAX;

    // ---- one-time gather into registers ----
    float zc[4][12];
    #pragma unroll
    for (int j = 0; j < 4; ++j) {
        if (j * 8 < degc) {
            int idx = j * 8 + g;
            int s = 0;
            if (idx < degc) s = csr[base + idx];
            const float4* zs4 = (const float4*)(zin + (size_t)s * KF + k * FAC);
            #pragma unroll
            for (int q = 0; q < 3; ++q) {
                float4 t = zs4[q];
                zc[j][q*4+0]=t.x; zc[j][q*4+1]=t.y; zc[j][q*4+2]=t.z; zc[j][q*4+3]=t.w;
            }
        } else {
            #pragma unroll
            for (int d = 0; d < 12; ++d) zc[j][d] = 0.f;
        }
    }

    for (int it = 0; it < ROUTIT; ++it) {
        float agg[12];
        #pragma unroll
        for (int d = 0; d < 12; ++d) agg[d] = 0.f;

        #pragma unroll
        for (int j = 0; j < 4; ++j) {
            if (j * 8 < degc) {                   // wave-uniform guard
                bool act = (j * 8 + g) < degc;
                float att = 0.f;
                #pragma unroll
                for (int d = 0; d < 12; ++d) att = fmaf(zc[j][d], c[d], att);
                float mx = att;
                mx = fmaxf(mx, __shfl_xor(mx, 1));
                mx = fmaxf(mx, __shfl_xor(mx, 2));
                mx = fmaxf(mx, __shfl_xor(mx, 4));
                float ex = __expf(att - mx);
                float sm = ex;
                sm += __shfl_xor(sm, 1);
                sm += __shfl_xor(sm, 2);
                sm += __shfl_xor(sm, 4);
                float p = __fdividef(ex, sm);
                if (act) {
                    #pragma unroll
                    for (int d = 0; d < 12; ++d) agg[d] = fmaf(p, zc[j][d], agg[d]);
                }
            }
        }

        // rare tail: deg > DMAX (P ~ 1e-4) — gather from global each iteration
        for (int t0 = DMAX; t0 < deg; t0 += 8) {
            int idx = t0 + g;
            bool act = idx < deg;
            int s = 0;
            if (act) s = csr[base + idx];
            const float4* zs4 = (const float4*)(zin + (size_t)s * KF + k * FAC);
            float zs[12];
            #pragma unroll
            for (int q = 0; q < 3; ++q) {
                float4 t = zs4[q];
                zs[q*4+0]=t.x; zs[q*4+1]=t.y; zs[q*4+2]=t.z; zs[q*4+3]=t.w;
            }
            float att = 0.f;
            #pragma unroll
            for (int d = 0; d < 12; ++d) att = fmaf(zs[d], c[d], att);
            float mx = att;
            mx = fmaxf(mx, __shfl_xor(mx, 1));
            mx = fmaxf(mx, __shfl_xor(mx, 2));
            mx = fmaxf(mx, __shfl_xor(mx, 4));
            float ex = __expf(att - mx);
            float sm = ex;
            sm += __shfl_xor(sm, 1);
            sm += __shfl_xor(sm, 2);
            sm += __shfl_xor(sm, 4);
            float p = __fdividef(ex, sm);
            if (act) {
                #pragma unroll
                for (int d = 0; d < 12; ++d) agg[d] = fmaf(p, zs[d], agg[d]);
            }
        }

        // reduce agg across the 8 edge-slot subgroups
        #pragma unroll
        for (int mask = 8; mask <= 32; mask <<= 1) {
            #pragma unroll
            for (int d = 0; d < 12; ++d) agg[d] += __shfl_xor(agg[d], mask);
        }
        // c = l2norm(z + agg) per capsule (in-lane)
        float v[12], ss = 0.f;
        #pragma unroll
        for (int d = 0; d < 12; ++d) { v[d] = z[d] + agg[d]; ss = fmaf(v[d], v[d], ss); }
        float inv = rsqrtf(ss + 1e-12f);
        #pragma unroll
        for (int d = 0; d < 12; ++d) c[d] = v[d] * inv;
    }

    if (g == 0) {
        float r[12], ss = 0.f;
        #pragma unroll
        for (int d = 0; d < 12; ++d) { r[d] = fmaxf(c[d], 0.f); ss = fmaf(r[d], r[d], ss); }
        float inv = rsqrtf(ss + 1e-12f);
        float* zo = znext + (size_t)node * KF + k * FAC;
        #pragma unroll
        for (int q = 0; q < 3; ++q) {
            float4 t;
            t.x = r[q*4+0]*inv; t.y = r[q*4+1]*inv; t.z = r[q*4+2]*inv; t.w = r[q*4+3]*inv;
            ((float4*)zo)[q] = t;
        }
        if (write_out) {
            float* oo = dout + (size_t)node * KF + k * FAC;
            #pragma unroll
            for (int q = 0; q < 3; ++q) {
                float4 t;
                t.x = r[q*4+0]; t.y = r[q*4+1]; t.z = r[q*4+2]; t.w = r[q*4+3];
                ((float4*)oo)[q] = t;
            }
        }
    }
}

extern "C" void kernel_launch(void* const* d_in, const int* in_sizes, int n_in,
                              void* d_out, int out_size, void* d_ws, size_t ws_size,
                              hipStream_t stream) {
    const float* X     = (const float*)d_in[0];
    const int*   edges = (const int*)d_in[1];
    const float* W     = (const float*)d_in[2];
    const float* b     = (const float*)d_in[3];
    float* out = (float*)d_out;
    char* ws = (char*)d_ws;

    float* zA      = (float*)(ws + OFF_ZA);
    float* zB      = (float*)(ws + OFF_ZB);
    int*   row_ptr = (int*)(ws + OFF_ROWPTR);
    int*   partial = (int*)(ws + OFF_PARTIAL);
    int*   cursor  = (int*)(ws + OFF_CURSOR);
    int*   bsums   = (int*)(ws + OFF_BSUMS);
    int*   csr     = (int*)(ws + OFF_CSR);
    float* Wt      = (float*)(ws + OFF_WT);

    const int* src = edges;            // edges[0, :]
    const int* dst = edges + M_EDGES;  // edges[1, :]

    // init projection + per-capsule normalize  (Z0 raw -> zB, normalized -> zA)
    wt_transpose<<<96, 256, 0, stream>>>(W, Wt);
    init_proj<<<(N_NODES + 31) / 32, 192, 0, stream>>>(X, Wt, b, zB);
    prep_norm<<<(N_NODES * KCAP + 255) / 256, 256, 0, stream>>>(zB, zA);

    // CSR by dst
    zero_counts<<<196, 256, 0, stream>>>(cursor);
    hist<<<(M_EDGES + 255) / 256, 256, 0, stream>>>(dst, cursor);
    scan1<<<196, 256, 0, stream>>>(cursor, partial, bsums);
    scan2<<<1, 256, 0, stream>>>(bsums, 196);
    finalize_rp<<<196, 256, 0, stream>>>(partial, bsums, row_ptr);
    cursor_init<<<196, 256, 0, stream>>>(row_ptr, cursor);
    csr_fill<<<(M_EDGES + 255) / 256, 256, 0, stream>>>(src, dst, cursor, csr);

    // 4 routing layers, ping-pong z buffers; last layer also writes d_out
    route<<<12500, 256, 0, stream>>>(zA, zB, nullptr, row_ptr, csr, 0);
    route<<<12500, 256, 0, stream>>>(zB, zA, nullptr, row_ptr, csr, 0);
    route<<<12500, 256, 0, stream>>>(zA, zB, nullptr, row_ptr, csr, 0);
    route<<<12500, 256, 0, stream>>>(zB, zA, out, row_ptr, csr, 1);
}

// Round 4
// 791.429 us; speedup vs baseline: 1.4388x; 1.2214x over previous
//
#include <hip/hip_runtime.h>
#include <math.h>

#define N_NODES 50000
#define M_EDGES 800000
#define INP 256
#define KCAP 8
#define FAC 12
#define KF 96            // K*FAC
#define ROUTIT 6
#define DMAX 24          // register-cached edges per node (6 slots x 4 subgroups)

// ---------------- ws layout (bytes) ----------------
#define OFF_ZA      0u
#define OFF_ZB      19200000u
#define OFF_ROWPTR  38400000u   // 50001 ints (padded)
#define OFF_PARTIAL 38600016u   // 50000 ints
#define OFF_CURSOR  38800016u   // 50000 ints (also used as counts)
#define OFF_BSUMS   39000016u   // 256 ints
#define OFF_CSR     39001040u   // 800000 ints
#define OFF_WT      42201040u   // 256*96 floats

// ---------- W transpose: Wt[i][kf] = W[k][i][f]  (i-major, kf-minor) ----------
__global__ void wt_transpose(const float* __restrict__ W, float* __restrict__ Wt) {
    int idx = blockIdx.x * 256 + threadIdx.x;
    if (idx >= INP * KF) return;
    int i = idx / KF, kf = idx % KF;
    int k = kf / FAC, f = kf % FAC;
    Wt[i * KF + kf] = W[(k * INP + i) * FAC + f];
}

// ---------- init: Z0[n][kf] = relu(X[n,:].Wt[:,kf] + b[kf]) ----------
// register-blocked 4 nodes x 4 kf per thread; block 192 = 8 node-quads x 24 kf-quads
__global__ __launch_bounds__(192) void init_proj(const float* __restrict__ X,
                                                 const float* __restrict__ Wt,
                                                 const float* __restrict__ b,
                                                 float* __restrict__ Z0) {
    int nq  = threadIdx.x / 24;          // 0..7
    int kfq = threadIdx.x % 24;          // 0..23
    int nb  = blockIdx.x * 32 + nq * 4;  // node base (4 nodes)
    int kf0 = kfq * 4;

    int nn[4];
    #pragma unroll
    for (int m = 0; m < 4; ++m) {
        int n = nb + m;
        nn[m] = n < N_NODES ? n : N_NODES - 1;  // clamp; discard at write
    }

    float acc[4][4];
    #pragma unroll
    for (int m = 0; m < 4; ++m)
        #pragma unroll
        for (int cc = 0; cc < 4; ++cc) acc[m][cc] = 0.f;

    for (int i4 = 0; i4 < INP / 4; ++i4) {
        float4 xv[4];
        #pragma unroll
        for (int m = 0; m < 4; ++m)
            xv[m] = ((const float4*)(X + (size_t)nn[m] * INP))[i4];
        float4 wv[4];
        #pragma unroll
        for (int r = 0; r < 4; ++r)
            wv[r] = *(const float4*)(Wt + (size_t)(i4 * 4 + r) * KF + kf0);
        #pragma unroll
        for (int m = 0; m < 4; ++m) {
            acc[m][0] = fmaf(xv[m].x, wv[0].x, acc[m][0]);
            acc[m][1] = fmaf(xv[m].x, wv[0].y, acc[m][1]);
            acc[m][2] = fmaf(xv[m].x, wv[0].z, acc[m][2]);
            acc[m][3] = fmaf(xv[m].x, wv[0].w, acc[m][3]);
            acc[m][0] = fmaf(xv[m].y, wv[1].x, acc[m][0]);
            acc[m][1] = fmaf(xv[m].y, wv[1].y, acc[m][1]);
            acc[m][2] = fmaf(xv[m].y, wv[1].z, acc[m][2]);
            acc[m][3] = fmaf(xv[m].y, wv[1].w, acc[m][3]);
            acc[m][0] = fmaf(xv[m].z, wv[2].x, acc[m][0]);
            acc[m][1] = fmaf(xv[m].z, wv[2].y, acc[m][1]);
            acc[m][2] = fmaf(xv[m].z, wv[2].z, acc[m][2]);
            acc[m][3] = fmaf(xv[m].z, wv[2].w, acc[m][3]);
            acc[m][0] = fmaf(xv[m].w, wv[3].x, acc[m][0]);
            acc[m][1] = fmaf(xv[m].w, wv[3].y, acc[m][1]);
            acc[m][2] = fmaf(xv[m].w, wv[3].z, acc[m][2]);
            acc[m][3] = fmaf(xv[m].w, wv[3].w, acc[m][3]);
        }
    }

    float4 bv = *(const float4*)(b + kf0);
    #pragma unroll
    for (int m = 0; m < 4; ++m) {
        int n = nb + m;
        if (n < N_NODES) {
            float4 o;
            o.x = fmaxf(acc[m][0] + bv.x, 0.f);
            o.y = fmaxf(acc[m][1] + bv.y, 0.f);
            o.z = fmaxf(acc[m][2] + bv.z, 0.f);
            o.w = fmaxf(acc[m][3] + bv.w, 0.f);
            *(float4*)(Z0 + (size_t)n * KF + kf0) = o;
        }
    }
}

// ---------- prep: per-capsule l2norm ----------
__global__ void prep_norm(const float* __restrict__ Z0, float* __restrict__ zb) {
    int cap = blockIdx.x * blockDim.x + threadIdx.x;
    if (cap >= N_NODES * KCAP) return;
    const float4* p = (const float4*)(Z0 + (size_t)cap * FAC);
    float4 a = p[0], bq = p[1], cq = p[2];
    float ss = a.x*a.x + a.y*a.y + a.z*a.z + a.w*a.w
             + bq.x*bq.x + bq.y*bq.y + bq.z*bq.z + bq.w*bq.w
             + cq.x*cq.x + cq.y*cq.y + cq.z*cq.z + cq.w*cq.w;
    float inv = rsqrtf(ss + 1e-12f);
    float4* o = (float4*)(zb + (size_t)cap * FAC);
    float4 r0, r1, r2;
    r0.x=a.x*inv;  r0.y=a.y*inv;  r0.z=a.z*inv;  r0.w=a.w*inv;
    r1.x=bq.x*inv; r1.y=bq.y*inv; r1.z=bq.z*inv; r1.w=bq.w*inv;
    r2.x=cq.x*inv; r2.y=cq.y*inv; r2.z=cq.z*inv; r2.w=cq.w*inv;
    o[0]=r0; o[1]=r1; o[2]=r2;
}

// ---------- CSR build ----------
__global__ void zero_counts(int* __restrict__ counts) {
    int i = blockIdx.x * 256 + threadIdx.x;
    if (i < N_NODES) counts[i] = 0;
}
__global__ void hist(const int* __restrict__ dst, int* __restrict__ counts) {
    int e = blockIdx.x * 256 + threadIdx.x;
    if (e < M_EDGES) atomicAdd(&counts[dst[e]], 1);
}
__global__ void scan1(const int* __restrict__ counts, int* __restrict__ partial,
                      int* __restrict__ bsums) {
    __shared__ int s[256];
    int t = threadIdx.x;
    int i = blockIdx.x * 256 + t;
    int v = (i < N_NODES) ? counts[i] : 0;
    s[t] = v; __syncthreads();
    for (int off = 1; off < 256; off <<= 1) {
        int tmp = (t >= off) ? s[t - off] : 0;
        __syncthreads();
        s[t] += tmp;
        __syncthreads();
    }
    if (i < N_NODES) partial[i] = s[t];
    if (t == 255) bsums[blockIdx.x] = s[t];
}
__global__ void scan2(int* __restrict__ bs, int nb) {
    __shared__ int s[256];
    int t = threadIdx.x;
    int v = (t < nb) ? bs[t] : 0;
    s[t] = v; __syncthreads();
    for (int off = 1; off < 256; off <<= 1) {
        int tmp = (t >= off) ? s[t - off] : 0;
        __syncthreads();
        s[t] += tmp;
        __syncthreads();
    }
    if (t < nb) bs[t] = s[t] - v;  // exclusive
}
__global__ void finalize_rp(const int* __restrict__ partial, const int* __restrict__ boffs,
                            int* __restrict__ row_ptr) {
    int i = blockIdx.x * 256 + threadIdx.x;
    if (i < N_NODES) row_ptr[i + 1] = partial[i] + boffs[i >> 8];
    if (i == 0) row_ptr[0] = 0;
}
__global__ void cursor_init(const int* __restrict__ row_ptr, int* __restrict__ cursor) {
    int i = blockIdx.x * 256 + threadIdx.x;
    if (i < N_NODES) cursor[i] = row_ptr[i];
}
__global__ void csr_fill(const int* __restrict__ src, const int* __restrict__ dst,
                         int* __restrict__ cursor, int* __restrict__ csr) {
    int e = blockIdx.x * 256 + threadIdx.x;
    if (e < M_EDGES) {
        int d = dst[e];
        int pos = atomicAdd(&cursor[d], 1);
        csr[pos] = src[e];
    }
}

// ---------- routing layer: TWO nodes per wave ----------
// lane = h*32 + gp*8 + k : h = node half, gp = edge slot (0..3), k = capsule (0..7)
// 24 edges/node cached in zc[6][12] (zero-padded -> inactive slots contribute
// exactly 0 to agg, no masking needed). Softmax has NO max-subtraction
// (z,c unit vectors => att in [-1,1], exp can't overflow; softmax is
// shift-invariant so result identical). Two 3-slot phase-major batches give
// 3 independent shuffle chains in flight. agg reduce = masks 8,16 only.
__global__ __launch_bounds__(256, 4) void route(const float* __restrict__ zin,
                                                float* __restrict__ znext,
                                                float* __restrict__ dout,
                                                const int* __restrict__ row_ptr,
                                                const int* __restrict__ csr,
                                                int write_out) {
    int wid  = (blockIdx.x * 256 + threadIdx.x) >> 6;   // 0..24999
    int lane = threadIdx.x & 63;
    int h  = lane >> 5;        // node within wave
    int gp = (lane >> 3) & 3;  // edge subgroup (4 per node)
    int k  = lane & 7;         // capsule
    int node = wid * 2 + h;    // 25000*2 == N_NODES exactly

    // own z (persistent) and c
    float z[12], c[12];
    {
        const float4* zr = (const float4*)(zin + (size_t)node * KF + k * FAC);
        #pragma unroll
        for (int q = 0; q < 3; ++q) {
            float4 t = zr[q];
            z[q*4+0]=t.x; z[q*4+1]=t.y; z[q*4+2]=t.z; z[q*4+3]=t.w;
        }
    }
    #pragma unroll
    for (int d = 0; d < 12; ++d) c[d] = z[d];

    int base = row_ptr[node];
    int deg  = row_ptr[node + 1] - base;
    int degc = deg < DMAX ? deg : DMAX;
    // wave-max degree (deg uniform within half; only cross-half exchange needed)
    int dm = deg;
    dm = max(dm, __shfl_xor(dm, 32));
    bool hasTail = dm > DMAX;

    // ---- one-time gather: 6 slots x 4 edges ----
    float zc[6][12];
    #pragma unroll
    for (int j = 0; j < 6; ++j) {
        int idx = j * 4 + gp;
        if (idx < degc) {
            int s = csr[base + idx];
            const float4* zs4 = (const float4*)(zin + (size_t)s * KF + k * FAC);
            #pragma unroll
            for (int q = 0; q < 3; ++q) {
                float4 t = zs4[q];
                zc[j][q*4+0]=t.x; zc[j][q*4+1]=t.y; zc[j][q*4+2]=t.z; zc[j][q*4+3]=t.w;
            }
        } else {
            #pragma unroll
            for (int d = 0; d < 12; ++d) zc[j][d] = 0.f;
        }
    }

    for (int it = 0; it < ROUTIT; ++it) {
        float agg[12];
        #pragma unroll
        for (int d = 0; d < 12; ++d) agg[d] = 0.f;

        // two phase-major batches of 3 slots each (3-wide ILP shuffle chains)
        #pragma unroll
        for (int half = 0; half < 2; ++half) {
            int j0 = half * 3;
            float ex[3], sm[3];
            #pragma unroll
            for (int jj = 0; jj < 3; ++jj) {
                float att = 0.f;
                #pragma unroll
                for (int d = 0; d < 12; ++d) att = fmaf(zc[j0+jj][d], c[d], att);
                ex[jj] = __expf(att);      // att in [-1,1]: no max needed
                sm[jj] = ex[jj];
            }
            #pragma unroll
            for (int m = 1; m <= 4; m <<= 1) {
                #pragma unroll
                for (int jj = 0; jj < 3; ++jj) sm[jj] += __shfl_xor(sm[jj], m);
            }
            #pragma unroll
            for (int jj = 0; jj < 3; ++jj) {
                float p = __fdividef(ex[jj], sm[jj]);
                // zc==0 for inactive slots -> contribution auto-zero
                #pragma unroll
                for (int d = 0; d < 12; ++d) agg[d] = fmaf(p, zc[j0+jj][d], agg[d]);
            }
        }

        // rare tail: deg > 24 (~2% of nodes) — global re-gather each iteration
        if (hasTail) {
            for (int t0 = DMAX; t0 < dm; t0 += 4) {
                int idx = t0 + gp;
                bool act = idx < deg;
                float zs[12];
                #pragma unroll
                for (int d = 0; d < 12; ++d) zs[d] = 0.f;
                if (act) {
                    int s = csr[base + idx];
                    const float4* zs4 = (const float4*)(zin + (size_t)s * KF + k * FAC);
                    #pragma unroll
                    for (int q = 0; q < 3; ++q) {
                        float4 t = zs4[q];
                        zs[q*4+0]=t.x; zs[q*4+1]=t.y; zs[q*4+2]=t.z; zs[q*4+3]=t.w;
                    }
                }
                float att = 0.f;
                #pragma unroll
                for (int d = 0; d < 12; ++d) att = fmaf(zs[d], c[d], att);
                float exv = __expf(att);
                float smv = exv;
                smv += __shfl_xor(smv, 1);
                smv += __shfl_xor(smv, 2);
                smv += __shfl_xor(smv, 4);
                float p = __fdividef(exv, smv);
                #pragma unroll
                for (int d = 0; d < 12; ++d) agg[d] = fmaf(p, zs[d], agg[d]);
            }
        }

        // reduce agg over the 4 edge subgroups (stay within the half: masks 8,16)
        #pragma unroll
        for (int d = 0; d < 12; ++d) agg[d] += __shfl_xor(agg[d], 8);
        #pragma unroll
        for (int d = 0; d < 12; ++d) agg[d] += __shfl_xor(agg[d], 16);

        // c = l2norm(z + agg)
        float ss = 0.f;
        float v[12];
        #pragma unroll
        for (int d = 0; d < 12; ++d) { v[d] = z[d] + agg[d]; ss = fmaf(v[d], v[d], ss); }
        float inv = rsqrtf(ss + 1e-12f);
        #pragma unroll
        for (int d = 0; d < 12; ++d) c[d] = v[d] * inv;
    }

    if (gp == 0) {
        float r[12], ss = 0.f;
        #pragma unroll
        for (int d = 0; d < 12; ++d) { r[d] = fmaxf(c[d], 0.f); ss = fmaf(r[d], r[d], ss); }
        float inv = rsqrtf(ss + 1e-12f);
        float* zo = znext + (size_t)node * KF + k * FAC;
        #pragma unroll
        for (int q = 0; q < 3; ++q) {
            float4 t;
            t.x = r[q*4+0]*inv; t.y = r[q*4+1]*inv; t.z = r[q*4+2]*inv; t.w = r[q*4+3]*inv;
            ((float4*)zo)[q] = t;
        }
        if (write_out) {
            float* oo = dout + (size_t)node * KF + k * FAC;
            #pragma unroll
            for (int q = 0; q < 3; ++q) {
                float4 t;
                t.x = r[q*4+0]; t.y = r[q*4+1]; t.z = r[q*4+2]; t.w = r[q*4+3];
                ((float4*)oo)[q] = t;
            }
        }
    }
}

extern "C" void kernel_launch(void* const* d_in, const int* in_sizes, int n_in,
                              void* d_out, int out_size, void* d_ws, size_t ws_size,
                              hipStream_t stream) {
    const float* X     = (const float*)d_in[0];
    const int*   edges = (const int*)d_in[1];
    const float* W     = (const float*)d_in[2];
    const float* b     = (const float*)d_in[3];
    float* out = (float*)d_out;
    char* ws = (char*)d_ws;

    float* zA      = (float*)(ws + OFF_ZA);
    float* zB      = (float*)(ws + OFF_ZB);
    int*   row_ptr = (int*)(ws + OFF_ROWPTR);
    int*   partial = (int*)(ws + OFF_PARTIAL);
    int*   cursor  = (int*)(ws + OFF_CURSOR);
    int*   bsums   = (int*)(ws + OFF_BSUMS);
    int*   csr     = (int*)(ws + OFF_CSR);
    float* Wt      = (float*)(ws + OFF_WT);

    const int* src = edges;            // edges[0, :]
    const int* dst = edges + M_EDGES;  // edges[1, :]

    // init projection + per-capsule normalize  (Z0 raw -> zB, normalized -> zA)
    wt_transpose<<<96, 256, 0, stream>>>(W, Wt);
    init_proj<<<(N_NODES + 31) / 32, 192, 0, stream>>>(X, Wt, b, zB);
    prep_norm<<<(N_NODES * KCAP + 255) / 256, 256, 0, stream>>>(zB, zA);

    // CSR by dst
    zero_counts<<<196, 256, 0, stream>>>(cursor);
    hist<<<(M_EDGES + 255) / 256, 256, 0, stream>>>(dst, cursor);
    scan1<<<196, 256, 0, stream>>>(cursor, partial, bsums);
    scan2<<<1, 256, 0, stream>>>(bsums, 196);
    finalize_rp<<<196, 256, 0, stream>>>(partial, bsums, row_ptr);
    cursor_init<<<196, 256, 0, stream>>>(row_ptr, cursor);
    csr_fill<<<(M_EDGES + 255) / 256, 256, 0, stream>>>(src, dst, cursor, csr);

    // 4 routing layers, ping-pong z buffers; last layer also writes d_out
    // grid: 25000 waves (2 nodes/wave) = 6250 blocks
    route<<<6250, 256, 0, stream>>>(zA, zB, nullptr, row_ptr, csr, 0);
    route<<<6250, 256, 0, stream>>>(zB, zA, nullptr, row_ptr, csr, 0);
    route<<<6250, 256, 0, stream>>>(zA, zB, nullptr, row_ptr, csr, 0);
    route<<<6250, 256, 0, stream>>>(zB, zA, out, row_ptr, csr, 1);
}

// Round 5
// 673.013 us; speedup vs baseline: 1.6920x; 1.1759x over previous
//
#include <hip/hip_runtime.h>
#include <math.h>

#define N_NODES 50000
#define M_EDGES 800000
#define INP 256
#define KCAP 8
#define FAC 12
#define KF 96            // K*FAC
#define ROUTIT 6
#define DMAX 24          // register-cached edges per node (6 slots x 4 subgroups)

// ---------------- ws layout (bytes) ----------------
#define OFF_ZA      0u
#define OFF_ZB      19200000u
#define OFF_ROWPTR  38400000u   // 50001 ints (padded)
#define OFF_PARTIAL 38600016u   // 50000 ints
#define OFF_CURSOR  38800016u   // 50000 ints (counts -> row starts)
#define OFF_BSUMS   39000016u   // 256 ints
#define OFF_CSR     39001040u   // 800000 ints
#define OFF_WT      42201040u   // 256*96 floats

// ---------- W transpose: Wt[i][kf] = W[k][i][f]  (i-major, kf-minor) ----------
__global__ void wt_transpose(const float* __restrict__ W, float* __restrict__ Wt) {
    int idx = blockIdx.x * 256 + threadIdx.x;
    if (idx >= INP * KF) return;
    int i = idx / KF, kf = idx % KF;
    int k = kf / FAC, f = kf % FAC;
    Wt[i * KF + kf] = W[(k * INP + i) * FAC + f];
}

// ---------- init: Z0[n][kf] = relu(X[n,:].Wt[:,kf] + b[kf]) ----------
// register-blocked 4 nodes x 4 kf per thread; block 192 = 8 node-quads x 24 kf-quads
__global__ __launch_bounds__(192) void init_proj(const float* __restrict__ X,
                                                 const float* __restrict__ Wt,
                                                 const float* __restrict__ b,
                                                 float* __restrict__ Z0) {
    int nq  = threadIdx.x / 24;          // 0..7
    int kfq = threadIdx.x % 24;          // 0..23
    int nb  = blockIdx.x * 32 + nq * 4;  // node base (4 nodes)
    int kf0 = kfq * 4;

    int nn[4];
    #pragma unroll
    for (int m = 0; m < 4; ++m) {
        int n = nb + m;
        nn[m] = n < N_NODES ? n : N_NODES - 1;  // clamp; discard at write
    }

    float acc[4][4];
    #pragma unroll
    for (int m = 0; m < 4; ++m)
        #pragma unroll
        for (int cc = 0; cc < 4; ++cc) acc[m][cc] = 0.f;

    for (int i4 = 0; i4 < INP / 4; ++i4) {
        float4 xv[4];
        #pragma unroll
        for (int m = 0; m < 4; ++m)
            xv[m] = ((const float4*)(X + (size_t)nn[m] * INP))[i4];
        float4 wv[4];
        #pragma unroll
        for (int r = 0; r < 4; ++r)
            wv[r] = *(const float4*)(Wt + (size_t)(i4 * 4 + r) * KF + kf0);
        #pragma unroll
        for (int m = 0; m < 4; ++m) {
            acc[m][0] = fmaf(xv[m].x, wv[0].x, acc[m][0]);
            acc[m][1] = fmaf(xv[m].x, wv[0].y, acc[m][1]);
            acc[m][2] = fmaf(xv[m].x, wv[0].z, acc[m][2]);
            acc[m][3] = fmaf(xv[m].x, wv[0].w, acc[m][3]);
            acc[m][0] = fmaf(xv[m].y, wv[1].x, acc[m][0]);
            acc[m][1] = fmaf(xv[m].y, wv[1].y, acc[m][1]);
            acc[m][2] = fmaf(xv[m].y, wv[1].z, acc[m][2]);
            acc[m][3] = fmaf(xv[m].y, wv[1].w, acc[m][3]);
            acc[m][0] = fmaf(xv[m].z, wv[2].x, acc[m][0]);
            acc[m][1] = fmaf(xv[m].z, wv[2].y, acc[m][1]);
            acc[m][2] = fmaf(xv[m].z, wv[2].z, acc[m][2]);
            acc[m][3] = fmaf(xv[m].z, wv[2].w, acc[m][3]);
            acc[m][0] = fmaf(xv[m].w, wv[3].x, acc[m][0]);
            acc[m][1] = fmaf(xv[m].w, wv[3].y, acc[m][1]);
            acc[m][2] = fmaf(xv[m].w, wv[3].z, acc[m][2]);
            acc[m][3] = fmaf(xv[m].w, wv[3].w, acc[m][3]);
        }
    }

    float4 bv = *(const float4*)(b + kf0);
    #pragma unroll
    for (int m = 0; m < 4; ++m) {
        int n = nb + m;
        if (n < N_NODES) {
            float4 o;
            o.x = fmaxf(acc[m][0] + bv.x, 0.f);
            o.y = fmaxf(acc[m][1] + bv.y, 0.f);
            o.z = fmaxf(acc[m][2] + bv.z, 0.f);
            o.w = fmaxf(acc[m][3] + bv.w, 0.f);
            *(float4*)(Z0 + (size_t)n * KF + kf0) = o;
        }
    }
}

// ---------- prep: per-capsule l2norm ----------
__global__ void prep_norm(const float* __restrict__ Z0, float* __restrict__ zb) {
    int cap = blockIdx.x * blockDim.x + threadIdx.x;
    if (cap >= N_NODES * KCAP) return;
    const float4* p = (const float4*)(Z0 + (size_t)cap * FAC);
    float4 a = p[0], bq = p[1], cq = p[2];
    float ss = a.x*a.x + a.y*a.y + a.z*a.z + a.w*a.w
             + bq.x*bq.x + bq.y*bq.y + bq.z*bq.z + bq.w*bq.w
             + cq.x*cq.x + cq.y*cq.y + cq.z*cq.z + cq.w*cq.w;
    float inv = rsqrtf(ss + 1e-12f);
    float4* o = (float4*)(zb + (size_t)cap * FAC);
    float4 r0, r1, r2;
    r0.x=a.x*inv;  r0.y=a.y*inv;  r0.z=a.z*inv;  r0.w=a.w*inv;
    r1.x=bq.x*inv; r1.y=bq.y*inv; r1.z=bq.z*inv; r1.w=bq.w*inv;
    r2.x=cq.x*inv; r2.y=cq.y*inv; r2.z=cq.z*inv; r2.w=cq.w*inv;
    o[0]=r0; o[1]=r1; o[2]=r2;
}

// ---------- CSR build ----------
__global__ void hist(const int* __restrict__ dst, int* __restrict__ counts) {
    int e = blockIdx.x * 256 + threadIdx.x;
    if (e < M_EDGES) atomicAdd(&counts[dst[e]], 1);
}
__global__ void scan1(const int* __restrict__ counts, int* __restrict__ partial,
                      int* __restrict__ bsums) {
    __shared__ int s[256];
    int t = threadIdx.x;
    int i = blockIdx.x * 256 + t;
    int v = (i < N_NODES) ? counts[i] : 0;
    s[t] = v; __syncthreads();
    for (int off = 1; off < 256; off <<= 1) {
        int tmp = (t >= off) ? s[t - off] : 0;
        __syncthreads();
        s[t] += tmp;
        __syncthreads();
    }
    if (i < N_NODES) partial[i] = s[t];
    if (t == 255) bsums[blockIdx.x] = s[t];
}
__global__ void scan2(int* __restrict__ bs, int nb) {
    __shared__ int s[256];
    int t = threadIdx.x;
    int v = (t < nb) ? bs[t] : 0;
    s[t] = v; __syncthreads();
    for (int off = 1; off < 256; off <<= 1) {
        int tmp = (t >= off) ? s[t - off] : 0;
        __syncthreads();
        s[t] += tmp;
        __syncthreads();
    }
    if (t < nb) bs[t] = s[t] - v;  // exclusive
}
// fused: row_ptr[i+1] = inclusive scan; cursor[i] = row start (= incl - counts[i])
__global__ void finalize_rp(const int* __restrict__ partial, const int* __restrict__ boffs,
                            const int* __restrict__ counts,
                            int* __restrict__ row_ptr, int* __restrict__ cursor) {
    int i = blockIdx.x * 256 + threadIdx.x;
    if (i < N_NODES) {
        int incl = partial[i] + boffs[i >> 8];
        row_ptr[i + 1] = incl;
        cursor[i] = incl - counts[i];
    }
    if (i == 0) row_ptr[0] = 0;
}
__global__ void csr_fill(const int* __restrict__ src, const int* __restrict__ dst,
                         int* __restrict__ cursor, int* __restrict__ csr) {
    int e = blockIdx.x * 256 + threadIdx.x;
    if (e < M_EDGES) {
        int d = dst[e];
        int pos = atomicAdd(&cursor[d], 1);
        csr[pos] = src[e];
    }
}

// ---------- routing layer: TWO nodes per wave ----------
// lane = h*32 + gp*8 + k : h = node half, gp = edge slot (0..3), k = capsule (0..7)
// 24 edges/node cached in zc[6][12] (zero-padded). No max-subtraction in softmax
// (z,c unit vectors => att in [-1,1]). launch_bounds(256,3): VGPR cap ~170 so the
// 72-float neighbor cache stays IN REGISTERS (round-4's (256,4) cap of 128 spilled
// it to scratch: WRITE_SIZE 19MB -> 137MB. 3 waves/SIMD occupancy is unchanged.)
__global__ __launch_bounds__(256, 3) void route(const float* __restrict__ zin,
                                                float* __restrict__ znext,
                                                float* __restrict__ dout,
                                                const int* __restrict__ row_ptr,
                                                const int* __restrict__ csr,
                                                int write_out) {
    int wid  = (blockIdx.x * 256 + threadIdx.x) >> 6;   // 0..24999
    int lane = threadIdx.x & 63;
    int h  = lane >> 5;        // node within wave
    int gp = (lane >> 3) & 3;  // edge subgroup (4 per node)
    int k  = lane & 7;         // capsule
    int node = wid * 2 + h;    // 25000*2 == N_NODES exactly

    // own z (persistent) and c
    float z[12], c[12];
    {
        const float4* zr = (const float4*)(zin + (size_t)node * KF + k * FAC);
        #pragma unroll
        for (int q = 0; q < 3; ++q) {
            float4 t = zr[q];
            z[q*4+0]=t.x; z[q*4+1]=t.y; z[q*4+2]=t.z; z[q*4+3]=t.w;
        }
    }
    #pragma unroll
    for (int d = 0; d < 12; ++d) c[d] = z[d];

    int base = row_ptr[node];
    int deg  = row_ptr[node + 1] - base;
    int degc = deg < DMAX ? deg : DMAX;
    // wave-max degree (deg uniform within half; only cross-half exchange needed)
    int dm = deg;
    dm = max(dm, __shfl_xor(dm, 32));
    bool hasTail = dm > DMAX;

    // ---- one-time gather: 6 slots x 4 edges ----
    float zc[6][12];
    #pragma unroll
    for (int j = 0; j < 6; ++j) {
        int idx = j * 4 + gp;
        if (idx < degc) {
            int s = csr[base + idx];
            const float4* zs4 = (const float4*)(zin + (size_t)s * KF + k * FAC);
            #pragma unroll
            for (int q = 0; q < 3; ++q) {
                float4 t = zs4[q];
                zc[j][q*4+0]=t.x; zc[j][q*4+1]=t.y; zc[j][q*4+2]=t.z; zc[j][q*4+3]=t.w;
            }
        } else {
            #pragma unroll
            for (int d = 0; d < 12; ++d) zc[j][d] = 0.f;
        }
    }

    for (int it = 0; it < ROUTIT; ++it) {
        float agg[12];
        #pragma unroll
        for (int d = 0; d < 12; ++d) agg[d] = 0.f;

        // two phase-major batches of 3 slots each (3-wide ILP shuffle chains)
        #pragma unroll
        for (int half = 0; half < 2; ++half) {
            int j0 = half * 3;
            float ex[3], sm[3];
            #pragma unroll
            for (int jj = 0; jj < 3; ++jj) {
                float att = 0.f;
                #pragma unroll
                for (int d = 0; d < 12; ++d) att = fmaf(zc[j0+jj][d], c[d], att);
                ex[jj] = __expf(att);      // att in [-1,1]: no max needed
                sm[jj] = ex[jj];
            }
            #pragma unroll
            for (int m = 1; m <= 4; m <<= 1) {
                #pragma unroll
                for (int jj = 0; jj < 3; ++jj) sm[jj] += __shfl_xor(sm[jj], m);
            }
            #pragma unroll
            for (int jj = 0; jj < 3; ++jj) {
                float p = __fdividef(ex[jj], sm[jj]);
                // zc==0 for inactive slots -> contribution auto-zero
                #pragma unroll
                for (int d = 0; d < 12; ++d) agg[d] = fmaf(p, zc[j0+jj][d], agg[d]);
            }
        }

        // rare tail: deg > 24 (~2% of nodes) — global re-gather each iteration
        if (hasTail) {
            for (int t0 = DMAX; t0 < dm; t0 += 4) {
                int idx = t0 + gp;
                bool act = idx < deg;
                float zs[12];
                #pragma unroll
                for (int d = 0; d < 12; ++d) zs[d] = 0.f;
                if (act) {
                    int s = csr[base + idx];
                    const float4* zs4 = (const float4*)(zin + (size_t)s * KF + k * FAC);
                    #pragma unroll
                    for (int q = 0; q < 3; ++q) {
                        float4 t = zs4[q];
                        zs[q*4+0]=t.x; zs[q*4+1]=t.y; zs[q*4+2]=t.z; zs[q*4+3]=t.w;
                    }
                }
                float att = 0.f;
                #pragma unroll
                for (int d = 0; d < 12; ++d) att = fmaf(zs[d], c[d], att);
                float exv = __expf(att);
                float smv = exv;
                smv += __shfl_xor(smv, 1);
                smv += __shfl_xor(smv, 2);
                smv += __shfl_xor(smv, 4);
                float p = __fdividef(exv, smv);
                #pragma unroll
                for (int d = 0; d < 12; ++d) agg[d] = fmaf(p, zs[d], agg[d]);
            }
        }

        // reduce agg over the 4 edge subgroups (stay within the half: masks 8,16)
        #pragma unroll
        for (int d = 0; d < 12; ++d) agg[d] += __shfl_xor(agg[d], 8);
        #pragma unroll
        for (int d = 0; d < 12; ++d) agg[d] += __shfl_xor(agg[d], 16);

        // c = l2norm(z + agg)
        float ss = 0.f;
        float v[12];
        #pragma unroll
        for (int d = 0; d < 12; ++d) { v[d] = z[d] + agg[d]; ss = fmaf(v[d], v[d], ss); }
        float inv = rsqrtf(ss + 1e-12f);
        #pragma unroll
        for (int d = 0; d < 12; ++d) c[d] = v[d] * inv;
    }

    if (gp == 0) {
        float r[12], ss = 0.f;
        #pragma unroll
        for (int d = 0; d < 12; ++d) { r[d] = fmaxf(c[d], 0.f); ss = fmaf(r[d], r[d], ss); }
        if (write_out) {
            // final layer: output is relu(c), un-normalized; znext is dead -> skip it
            float* oo = dout + (size_t)node * KF + k * FAC;
            #pragma unroll
            for (int q = 0; q < 3; ++q) {
                float4 t;
                t.x = r[q*4+0]; t.y = r[q*4+1]; t.z = r[q*4+2]; t.w = r[q*4+3];
                ((float4*)oo)[q] = t;
            }
        } else {
            float inv = rsqrtf(ss + 1e-12f);
            float* zo = znext + (size_t)node * KF + k * FAC;
            #pragma unroll
            for (int q = 0; q < 3; ++q) {
                float4 t;
                t.x = r[q*4+0]*inv; t.y = r[q*4+1]*inv; t.z = r[q*4+2]*inv; t.w = r[q*4+3]*inv;
                ((float4*)zo)[q] = t;
            }
        }
    }
}

extern "C" void kernel_launch(void* const* d_in, const int* in_sizes, int n_in,
                              void* d_out, int out_size, void* d_ws, size_t ws_size,
                              hipStream_t stream) {
    const float* X     = (const float*)d_in[0];
    const int*   edges = (const int*)d_in[1];
    const float* W     = (const float*)d_in[2];
    const float* b     = (const float*)d_in[3];
    float* out = (float*)d_out;
    char* ws = (char*)d_ws;

    float* zA      = (float*)(ws + OFF_ZA);
    float* zB      = (float*)(ws + OFF_ZB);
    int*   row_ptr = (int*)(ws + OFF_ROWPTR);
    int*   partial = (int*)(ws + OFF_PARTIAL);
    int*   cursor  = (int*)(ws + OFF_CURSOR);
    int*   bsums   = (int*)(ws + OFF_BSUMS);
    int*   csr     = (int*)(ws + OFF_CSR);
    float* Wt      = (float*)(ws + OFF_WT);

    const int* src = edges;            // edges[0, :]
    const int* dst = edges + M_EDGES;  // edges[1, :]

    // init projection + per-capsule normalize  (Z0 raw -> zB, normalized -> zA)
    wt_transpose<<<96, 256, 0, stream>>>(W, Wt);
    init_proj<<<(N_NODES + 31) / 32, 192, 0, stream>>>(X, Wt, b, zB);
    prep_norm<<<(N_NODES * KCAP + 255) / 256, 256, 0, stream>>>(zB, zA);

    // CSR by dst (counts live in `cursor`; finalize_rp converts to row starts)
    hipMemsetAsync(cursor, 0, N_NODES * sizeof(int), stream);
    hist<<<(M_EDGES + 255) / 256, 256, 0, stream>>>(dst, cursor);
    scan1<<<196, 256, 0, stream>>>(cursor, partial, bsums);
    scan2<<<1, 256, 0, stream>>>(bsums, 196);
    finalize_rp<<<196, 256, 0, stream>>>(partial, bsums, cursor, row_ptr, cursor);
    csr_fill<<<(M_EDGES + 255) / 256, 256, 0, stream>>>(src, dst, cursor, csr);

    // 4 routing layers, ping-pong z buffers; last layer writes d_out only
    route<<<6250, 256, 0, stream>>>(zA, zB, nullptr, row_ptr, csr, 0);
    route<<<6250, 256, 0, stream>>>(zB, zA, nullptr, row_ptr, csr, 0);
    route<<<6250, 256, 0, stream>>>(zA, zB, nullptr, row_ptr, csr, 0);
    route<<<6250, 256, 0, stream>>>(zB, zA, out, row_ptr, csr, 1);
}